// Round 1
// baseline (657.015 us; speedup 1.0000x reference)
//
#include <hip/hip_runtime.h>
#include <hip/hip_bf16.h>

#define HF 96   // feature/hidden dim
#define GG 64
#define SB 64   // scan blocks per direction

typedef __attribute__((ext_vector_type(8))) short bf16x8;
typedef __attribute__((ext_vector_type(4))) float f32x4;

__device__ __forceinline__ unsigned short f2bf(float f) {
    unsigned u = __float_as_uint(f);
    unsigned r = (u + 0x7FFFu + ((u >> 16) & 1u)) >> 16;
    return (unsigned short)r;
}
__device__ __forceinline__ float bf2f(unsigned short h) {
    return __uint_as_float(((unsigned)h) << 16);
}

// ---------------- degree counts + slot assignment ----------------
__global__ void count_kernel(const int* __restrict__ ei, int* __restrict__ cnt_dst,
                             int* __restrict__ cnt_src, int* __restrict__ slot_d,
                             int* __restrict__ slot_s, int E) {
    int e = blockIdx.x * blockDim.x + threadIdx.x;
    if (e >= E) return;
    int s = ei[e];
    int d = ei[E + e];
    slot_d[e] = atomicAdd(&cnt_dst[d], 1);
    slot_s[e] = atomicAdd(&cnt_src[s], 1);
}

// ---------------- 3-phase exclusive scan ----------------
__global__ __launch_bounds__(256) void scan_phase1(const int* __restrict__ cnt0,
                                                   const int* __restrict__ cnt1,
                                                   int* __restrict__ off0,
                                                   int* __restrict__ off1,
                                                   int* __restrict__ bsum, int N, int CH) {
    int dir = blockIdx.y;
    const int* cnt = dir ? cnt1 : cnt0;
    int* off = dir ? off1 : off0;
    int base = blockIdx.x * CH;
    int end = base + CH; if (end > N) end = N;
    __shared__ int buf[256];
    int carry = 0;
    for (int s = base; s < end; s += 256) {
        int i = s + threadIdx.x;
        int v = (i < end) ? cnt[i] : 0;
        buf[threadIdx.x] = v;
        __syncthreads();
        for (int st = 1; st < 256; st <<= 1) {
            int tv = (threadIdx.x >= st) ? buf[threadIdx.x - st] : 0;
            __syncthreads();
            buf[threadIdx.x] += tv;
            __syncthreads();
        }
        if (i < end) off[i] = carry + buf[threadIdx.x] - v;
        carry += buf[255];
        __syncthreads();
    }
    if (threadIdx.x == 0) bsum[dir * SB + blockIdx.x] = carry;
}

__global__ __launch_bounds__(64) void scan_phase2(int* __restrict__ bsum, int* __restrict__ boff,
                                                  int* __restrict__ off0, int* __restrict__ off1,
                                                  int N) {
    int dir = blockIdx.x;
    __shared__ int buf[SB];
    int v = bsum[dir * SB + threadIdx.x];
    buf[threadIdx.x] = v;
    __syncthreads();
    for (int st = 1; st < SB; st <<= 1) {
        int tv = (threadIdx.x >= st) ? buf[threadIdx.x - st] : 0;
        __syncthreads();
        buf[threadIdx.x] += tv;
        __syncthreads();
    }
    boff[dir * SB + threadIdx.x] = buf[threadIdx.x] - v;
    if (threadIdx.x == SB - 1) {
        int* off = dir ? off1 : off0;
        off[N] = buf[SB - 1];
    }
}

__global__ void scan_phase3(int* __restrict__ off0, int* __restrict__ off1,
                            const int* __restrict__ boff, int N, int CH) {
    int dir = blockIdx.y;
    int* off = dir ? off1 : off0;
    int i = blockIdx.x * 256 + threadIdx.x;
    if (i >= N) return;
    off[i] += boff[dir * SB + i / CH];
}

// ---------------- CSR fill (atomic-free: slots precomputed) ----------------
__global__ void fill_kernel(const int* __restrict__ ei, const int* __restrict__ off_dst,
                            const int* __restrict__ off_src, const int* __restrict__ slot_d,
                            const int* __restrict__ slot_s, int* __restrict__ nbr_dst,
                            int* __restrict__ nbr_src, int E) {
    int e = blockIdx.x * blockDim.x + threadIdx.x;
    if (e >= E) return;
    int s = ei[e];
    int d = ei[E + e];
    nbr_dst[off_dst[d] + slot_d[e]] = s;
    nbr_src[off_src[s] + slot_s[e]] = d;
}

// ---------------- weight prep: transpose + bf16 hi/lo split ----------------
__global__ void prep_kernel(const float* __restrict__ Wself, const float* __restrict__ Wsd,
                            const float* __restrict__ Wds, const float* __restrict__ bself,
                            const float* __restrict__ bsd, const float* __restrict__ bds,
                            unsigned short* __restrict__ Whi, unsigned short* __restrict__ Wlo,
                            float* __restrict__ bc) {
    int idx = blockIdx.x * 256 + threadIdx.x;
    if (idx < HF * 288) {
        int j = idx / 288;
        int kk = idx % 288;
        int m = kk / HF, k = kk % HF;
        const float* W = (m == 0) ? Wself : (m == 1) ? Wsd : Wds;
        float w = W[k * HF + j];
        unsigned short hi = f2bf(w);
        float rem = w - bf2f(hi);
        Whi[idx] = hi;
        Wlo[idx] = f2bf(rem);
    } else if (idx < HF * 288 + HF) {
        int j = idx - HF * 288;
        bc[j] = bself[j] + 0.5f * (bsd[j] + bds[j]);
    }
}

// ---------------- slab transpose: x[N][96] -> xg[8][N][12] ----------------
// Each 12-col slice is a contiguous 2.4 MB slab => per-XCD L2-resident, no
// cache-line sharing between slices.
__global__ __launch_bounds__(256) void slab_kernel(const float* __restrict__ x,
                                                   float* __restrict__ xg, int N) {
    int t = blockIdx.x * 256 + threadIdx.x;
    int n = t / 24, q = t % 24;
    if (n >= N) return;
    float4 v = *(const float4*)(x + (long long)n * HF + q * 4);
    int s = q / 3, c = q % 3;
    *(float4*)(xg + ((long long)s * N + n) * 12 + c * 4) = v;
}

// ---------------- gather-mean, XCD-sliced (12 cols per XCD via bid%8) ----------------
// Input in slab layout xg[8][N][12]; slice = blockIdx.x % 8 rides the default
// round-robin workgroup->XCD dispatch so each XCD streams only its own 2.4 MB slab.
// 3 threads per (node,dir) pair, one float4 each. ALPHA=0.5 folded into inv.
#define PPB 85   // pairs per block (256 threads / 3, lane 255 idle)
__global__ __launch_bounds__(256) void gather_kernel(
        const float* __restrict__ xg,
        const int* __restrict__ off_dst, const int* __restrict__ nbr_dst,
        const int* __restrict__ off_src, const int* __restrict__ nbr_src,
        float* __restrict__ agg_sd, float* __restrict__ agg_ds, int N) {
    int slice = blockIdx.x & 7;
    int grp = blockIdx.x >> 3;
    int tp = threadIdx.x / 3;
    int c = threadIdx.x % 3;
    if (tp >= PPB) return;
    int P = grp * PPB + tp;
    if (P >= 2 * N) return;
    int dir = (P >= N) ? 1 : 0;
    int n = P - dir * N;
    const int* off = dir ? off_src : off_dst;
    const int* nbr = dir ? nbr_src : nbr_dst;
    float* agg = dir ? agg_ds : agg_sd;

    int b = off[n], e = off[n + 1];
    const float* xq = xg + (long long)slice * N * 12 + c * 4;
    float4 a0 = make_float4(0.f, 0.f, 0.f, 0.f);
    float4 a1 = make_float4(0.f, 0.f, 0.f, 0.f);
    float4 a2 = make_float4(0.f, 0.f, 0.f, 0.f);
    float4 a3 = make_float4(0.f, 0.f, 0.f, 0.f);
    int i = b;
    for (; i + 4 <= e; i += 4) {
        int i0 = nbr[i + 0], i1 = nbr[i + 1], i2 = nbr[i + 2], i3 = nbr[i + 3];
        float4 v0 = *(const float4*)(xq + (long long)i0 * 12);
        float4 v1 = *(const float4*)(xq + (long long)i1 * 12);
        float4 v2 = *(const float4*)(xq + (long long)i2 * 12);
        float4 v3 = *(const float4*)(xq + (long long)i3 * 12);
        a0.x += v0.x; a0.y += v0.y; a0.z += v0.z; a0.w += v0.w;
        a1.x += v1.x; a1.y += v1.y; a1.z += v1.z; a1.w += v1.w;
        a2.x += v2.x; a2.y += v2.y; a2.z += v2.z; a2.w += v2.w;
        a3.x += v3.x; a3.y += v3.y; a3.z += v3.z; a3.w += v3.w;
    }
    for (; i < e; i++) {
        int i0 = nbr[i];
        float4 v0 = *(const float4*)(xq + (long long)i0 * 12);
        a0.x += v0.x; a0.y += v0.y; a0.z += v0.z; a0.w += v0.w;
    }
    float4 acc;
    acc.x = (a0.x + a1.x) + (a2.x + a3.x);
    acc.y = (a0.y + a1.y) + (a2.y + a3.y);
    acc.z = (a0.z + a1.z) + (a2.z + a3.z);
    acc.w = (a0.w + a1.w) + (a2.w + a3.w);
    float inv = 0.5f / fmaxf((float)(e - b), 1.0f);   // ALPHA=0.5 folded (exact pow2 scale)
    acc.x *= inv; acc.y *= inv; acc.z *= inv; acc.w *= inv;
    *(float4*)(agg + (long long)n * HF + slice * 12 + c * 4) = acc;
}

// ---------------- sage GEMM v3: MFMA bf16 hi/lo split (3-mfma fp32 emulation) ----------------
// C[N x 96] = relu([x | agg_sd | agg_ds](N x 288) @ W(288 x 96) + bc)
// A x-part read from slab layout xg[8][N][12]; agg parts row-major.
// Output: slab layout if slab_out (feeds next layer's gather+GEMM), else row-major (pool).
#define LPAD 40
__global__ __launch_bounds__(256) void sage_mfma(
        const float* __restrict__ xg, const float* __restrict__ agg_sd,
        const float* __restrict__ agg_ds,
        const unsigned short* __restrict__ Whi_g, const unsigned short* __restrict__ Wlo_g,
        const float* __restrict__ bc,
        float* __restrict__ out, int slab_out, int N) {
    __shared__ __align__(16) unsigned short Ahi[64 * LPAD];
    __shared__ __align__(16) unsigned short Alo[64 * LPAD];
    __shared__ __align__(16) unsigned short Whi[96 * LPAD];
    __shared__ __align__(16) unsigned short Wlo[96 * LPAD];

    const int tx = threadIdx.x;
    const int lane = tx & 63;
    const int wid = tx >> 6;
    const int wr = (wid >> 1) * 32;   // wave row offset in block tile
    const int wc = (wid & 1) * 48;    // wave col offset
    const int m = lane & 15;
    const int quad = lane >> 4;
    const int row0 = blockIdx.x * 64;

    // staging indices
    const int arow = tx >> 2;         // 0..63
    const int aq = tx & 3;            // 0..3 (8 floats each)
    int argc = row0 + arow; if (argc > N - 1) argc = N - 1;

    f32x4 acc[2][3];
#pragma unroll
    for (int rt = 0; rt < 2; rt++)
#pragma unroll
        for (int ct = 0; ct < 3; ct++) acc[rt][ct] = (f32x4){0.f, 0.f, 0.f, 0.f};

    for (int kt = 0; kt < 9; kt++) {
        const int koff = (kt % 3) * 32;          // k offset within the 96-wide source
        const int kglob = kt * 32;               // k offset in the 288 concat

        // ---- stage A: 64x32 fp32 -> bf16 hi/lo (1 x 8 floats per thread)
        {
            float4 v0, v1;
            const int c0 = koff + aq * 8;
            if (kt < 3) {
                // slab layout: col c -> slab c/12, inner c%12. A float4 at a
                // multiple-of-4 column offset never crosses a 12-wide slab.
                int s0i = c0 / 12, r0 = c0 % 12;
                int c1 = c0 + 4;
                int s1i = c1 / 12, r1 = c1 % 12;
                v0 = *(const float4*)(xg + ((long long)s0i * N + argc) * 12 + r0);
                v1 = *(const float4*)(xg + ((long long)s1i * N + argc) * 12 + r1);
            } else {
                const float* A = (kt < 6) ? agg_sd : agg_ds;
                const float* Ar = A + (long long)argc * HF + c0;
                v0 = *(const float4*)(Ar + 0);
                v1 = *(const float4*)(Ar + 4);
            }
            float f[8] = {v0.x, v0.y, v0.z, v0.w, v1.x, v1.y, v1.z, v1.w};
            bf16x8 hv, lv;
#pragma unroll
            for (int i = 0; i < 8; i++) {
                unsigned short h = f2bf(f[i]);
                hv[i] = (short)h;
                lv[i] = (short)f2bf(f[i] - bf2f(h));
            }
            *(bf16x8*)&Ahi[arow * LPAD + aq * 8] = hv;
            *(bf16x8*)&Alo[arow * LPAD + aq * 8] = lv;
        }
        // ---- stage W: 96x32 bf16 hi/lo, pre-split in global (copy 16B chunks)
        for (int s = tx; s < 384; s += 256) {
            int n = s >> 2, q2 = s & 3;
            long long go = (long long)n * 288 + kglob + q2 * 8;
            *(bf16x8*)&Whi[n * LPAD + q2 * 8] = *(const bf16x8*)(Whi_g + go);
            *(bf16x8*)&Wlo[n * LPAD + q2 * 8] = *(const bf16x8*)(Wlo_g + go);
        }
        __syncthreads();

        // ---- fragments
        bf16x8 ah[2], al[2], bh[3], bl[3];
#pragma unroll
        for (int rt = 0; rt < 2; rt++) {
            int r = (wr + rt * 16 + m) * LPAD + quad * 8;
            ah[rt] = *(const bf16x8*)&Ahi[r];
            al[rt] = *(const bf16x8*)&Alo[r];
        }
#pragma unroll
        for (int ct = 0; ct < 3; ct++) {
            int r = (wc + ct * 16 + m) * LPAD + quad * 8;
            bh[ct] = *(const bf16x8*)&Whi[r];
            bl[ct] = *(const bf16x8*)&Wlo[r];
        }
#pragma unroll
        for (int rt = 0; rt < 2; rt++)
#pragma unroll
            for (int ct = 0; ct < 3; ct++) {
                acc[rt][ct] = __builtin_amdgcn_mfma_f32_16x16x32_bf16(ah[rt], bh[ct], acc[rt][ct], 0, 0, 0);
                acc[rt][ct] = __builtin_amdgcn_mfma_f32_16x16x32_bf16(ah[rt], bl[ct], acc[rt][ct], 0, 0, 0);
                acc[rt][ct] = __builtin_amdgcn_mfma_f32_16x16x32_bf16(al[rt], bh[ct], acc[rt][ct], 0, 0, 0);
            }
        __syncthreads();
    }

    // ---- epilogue: bias + relu + store (C/D: col=lane&15, row=quad*4+reg)
#pragma unroll
    for (int ct = 0; ct < 3; ct++) {
        int col = wc + ct * 16 + m;
        float bcv = bc[col];
        if (slab_out) {
            int sidx = col / 12, cc = col % 12;
            float* base = out + (long long)sidx * N * 12 + cc;
#pragma unroll
            for (int rt = 0; rt < 2; rt++) {
#pragma unroll
                for (int reg = 0; reg < 4; reg++) {
                    int r = row0 + wr + rt * 16 + quad * 4 + reg;
                    if (r < N) base[(long long)r * 12] = fmaxf(acc[rt][ct][reg] + bcv, 0.f);
                }
            }
        } else {
#pragma unroll
            for (int rt = 0; rt < 2; rt++) {
#pragma unroll
                for (int reg = 0; reg < 4; reg++) {
                    int r = row0 + wr + rt * 16 + quad * 4 + reg;
                    if (r < N) out[(long long)r * HF + col] = fmaxf(acc[rt][ct][reg] + bcv, 0.f);
                }
            }
        }
    }
}

// ---------------- segment max pool (batch sorted) ----------------
#define POOL_CHUNK 128
__global__ void pool_kernel(const float* __restrict__ h, const int* __restrict__ batch,
                            unsigned* __restrict__ g, int N) {
    int j = threadIdx.x;
    if (j >= HF) return;
    int n0 = blockIdx.x * POOL_CHUNK;
    int end = n0 + POOL_CHUNK;
    if (end > N) end = N;
    float cur = 0.0f;
    int curb = -1;
    for (int n = n0; n < end; n++) {
        int b = batch[n];
        float v = h[(long long)n * HF + j];
        if (b != curb) {
            if (curb >= 0) atomicMax(&g[curb * HF + j], __float_as_uint(cur));
            curb = b;
            cur = v;
        } else {
            cur = fmaxf(cur, v);
        }
    }
    if (curb >= 0) atomicMax(&g[curb * HF + j], __float_as_uint(cur));
}

// ---------------- final MLP ----------------
__global__ void mlp_kernel(const unsigned* __restrict__ g, const float* __restrict__ lin1_w,
                           const float* __restrict__ lin1_b, const float* __restrict__ lin2_w,
                           const float* __restrict__ lin2_b, float* __restrict__ out) {
    int gi = threadIdx.x;
    if (gi >= GG) return;
    float h5[5];
#pragma unroll
    for (int hh = 0; hh < 5; hh++) {
        float acc = lin1_b[hh];
#pragma unroll 8
        for (int k = 0; k < HF; k++)
            acc = fmaf(__uint_as_float(g[gi * HF + k]), lin1_w[k * 5 + hh], acc);
        h5[hh] = fmaxf(acc, 0.0f);
    }
    float o = lin2_b[0];
#pragma unroll
    for (int hh = 0; hh < 5; hh++) o = fmaf(h5[hh], lin2_w[hh * 1 + 0], o);
    out[gi] = o;
}

extern "C" void kernel_launch(void* const* d_in, const int* in_sizes, int n_in,
                              void* d_out, int out_size, void* d_ws, size_t ws_size,
                              hipStream_t stream) {
    const float* x     = (const float*)d_in[0];
    const int*   ei    = (const int*)d_in[1];
    const int*   batch = (const int*)d_in[2];
    const float* W[3][3];
    const float* B[3][3];
    for (int l = 0; l < 3; l++) {
        for (int t = 0; t < 3; t++) W[l][t] = (const float*)d_in[3 + l * 6 + t];
        for (int t = 0; t < 3; t++) B[l][t] = (const float*)d_in[3 + l * 6 + 3 + t];
    }
    const float* lin1_w = (const float*)d_in[21];
    const float* lin1_b = (const float*)d_in[22];
    const float* lin2_w = (const float*)d_in[23];
    const float* lin2_b = (const float*)d_in[24];

    const int N = in_sizes[0] / HF;
    const int E = in_sizes[1] / 2;
    const long long NH = (long long)N * HF;

    // workspace layout (same total float footprint as before: 2 slab ping-pong + 2 agg)
    float* s0      = (float*)d_ws;            // slab buffer A (slab(x), then slab(h2))
    float* s1      = s0 + NH;                 // slab buffer B (slab(h1), then h3 row-major)
    float* agg_sd  = s1 + NH;
    float* agg_ds  = agg_sd + NH;
    int*   cnt_dst = (int*)(agg_ds + NH);
    int*   cnt_src = cnt_dst + N;
    int*   off_dst = cnt_src + N;           // N+1
    int*   off_src = off_dst + (N + 1);     // N+1
    int*   nbr_dst = off_src + (N + 1);     // E
    int*   nbr_src = nbr_dst + E;           // E
    int*   slot_d  = nbr_src + E;           // E
    int*   slot_s  = slot_d + E;            // E
    int*   bsum    = slot_s + E;            // 2*SB
    int*   boff    = bsum + 2 * SB;         // 2*SB
    float* bc3     = (float*)(boff + 2 * SB);   // 3*96
    // align to 16B for bf16 weight arrays
    uintptr_t p = (uintptr_t)(bc3 + 3 * HF);
    p = (p + 15) & ~(uintptr_t)15;
    unsigned short* Whi3 = (unsigned short*)p;          // 3 * 96*288
    unsigned short* Wlo3 = Whi3 + 3 * HF * 288;         // 3 * 96*288
    uintptr_t p2 = (uintptr_t)(Wlo3 + 3 * HF * 288);
    p2 = (p2 + 15) & ~(uintptr_t)15;
    unsigned* g = (unsigned*)p2;

    hipMemsetAsync(cnt_dst, 0, (size_t)2 * N * sizeof(int), stream);
    hipMemsetAsync(g, 0, (size_t)GG * HF * sizeof(unsigned), stream);

    // weight prep (independent of graph build)
    const int prep_blocks = (HF * 288 + HF + 255) / 256;
    for (int l = 0; l < 3; l++)
        prep_kernel<<<prep_blocks, 256, 0, stream>>>(
            W[l][0], W[l][1], W[l][2], B[l][0], B[l][1], B[l][2],
            Whi3 + (long long)l * HF * 288, Wlo3 + (long long)l * HF * 288, bc3 + l * HF);

    // slabify x
    slab_kernel<<<(int)((NH / 4 + 255) / 256), 256, 0, stream>>>(x, s0, N);

    const int CH = (N + SB - 1) / SB;
    count_kernel<<<(E + 255) / 256, 256, 0, stream>>>(ei, cnt_dst, cnt_src, slot_d, slot_s, E);
    scan_phase1<<<dim3(SB, 2), 256, 0, stream>>>(cnt_dst, cnt_src, off_dst, off_src, bsum, N, CH);
    scan_phase2<<<2, SB, 0, stream>>>(bsum, boff, off_dst, off_src, N);
    scan_phase3<<<dim3((N + 255) / 256, 2), 256, 0, stream>>>(off_dst, off_src, boff, N, CH);
    fill_kernel<<<(E + 255) / 256, 256, 0, stream>>>(ei, off_dst, off_src,
                                                     slot_d, slot_s, nbr_dst, nbr_src, E);

    const int bps = (2 * N + PPB - 1) / PPB;       // blocks per slice
    const int gather_blocks = bps * 8;
    const int gemm_blocks = (N + 63) / 64;
    const int pool_blocks = (N + POOL_CHUNK - 1) / POOL_CHUNK;

    // slab ping-pong: slab(x)=s0 -> h1 slab=s1 -> h2 slab=s0 -> h3 row-major=s1
    const float* slab_in[3] = { s0, s1, s0 };
    float*       outp[3]    = { s1, s0, s1 };
    for (int l = 0; l < 3; l++) {
        gather_kernel<<<gather_blocks, 256, 0, stream>>>(
            slab_in[l], off_dst, nbr_dst, off_src, nbr_src, agg_sd, agg_ds, N);
        sage_mfma<<<gemm_blocks, 256, 0, stream>>>(
            slab_in[l], agg_sd, agg_ds,
            Whi3 + (long long)l * HF * 288, Wlo3 + (long long)l * HF * 288,
            bc3 + l * HF, outp[l], (l < 2) ? 1 : 0, N);
    }

    pool_kernel<<<pool_blocks, 128, 0, stream>>>(s1, batch, g, N);
    mlp_kernel<<<1, 64, 0, stream>>>(g, lin1_w, lin1_b, lin2_w, lin2_b, (float*)d_out);
}

// Round 2
// 581.053 us; speedup vs baseline: 1.1307x; 1.1307x over previous
//
#include <hip/hip_runtime.h>
#include <hip/hip_bf16.h>

#define HF 96   // feature/hidden dim
#define GG 64
#define SB 64   // scan blocks per direction

typedef __attribute__((ext_vector_type(8))) short bf16x8;
typedef __attribute__((ext_vector_type(4))) float f32x4;
typedef unsigned int uint;

__device__ __forceinline__ unsigned short f2bf(float f) {
    unsigned u = __float_as_uint(f);
    unsigned r = (u + 0x7FFFu + ((u >> 16) & 1u)) >> 16;
    return (unsigned short)r;
}
__device__ __forceinline__ float bf2f(unsigned short h) {
    return __uint_as_float(((unsigned)h) << 16);
}

// Pack 4 floats into {hi0..3, lo0..3} bf16 (uint4 = 16B)
__device__ __forceinline__ uint4 pack_hilo4(float f0, float f1, float f2, float f3) {
    unsigned short h0 = f2bf(f0), h1 = f2bf(f1), h2 = f2bf(f2), h3 = f2bf(f3);
    unsigned short l0 = f2bf(f0 - bf2f(h0)), l1 = f2bf(f1 - bf2f(h1));
    unsigned short l2 = f2bf(f2 - bf2f(h2)), l3 = f2bf(f3 - bf2f(h3));
    uint4 o;
    o.x = (uint)h0 | ((uint)h1 << 16);
    o.y = (uint)h2 | ((uint)h3 << 16);
    o.z = (uint)l0 | ((uint)l1 << 16);
    o.w = (uint)l2 | ((uint)l3 << 16);
    return o;
}

// Accumulate 4 reconstructed floats (hi+lo) from a {hi4,lo4} chunk into a float4
__device__ __forceinline__ void acc_hilo4(float4& a, uint4 w) {
    a.x += __uint_as_float(w.x << 16) + __uint_as_float(w.z << 16);
    a.y += __uint_as_float(w.x & 0xFFFF0000u) + __uint_as_float(w.z & 0xFFFF0000u);
    a.z += __uint_as_float(w.y << 16) + __uint_as_float(w.w << 16);
    a.w += __uint_as_float(w.y & 0xFFFF0000u) + __uint_as_float(w.w & 0xFFFF0000u);
}

// ---------------- degree counts + slot assignment ----------------
__global__ void count_kernel(const int* __restrict__ ei, int* __restrict__ cnt_dst,
                             int* __restrict__ cnt_src, int* __restrict__ slot_d,
                             int* __restrict__ slot_s, int E) {
    int e = blockIdx.x * blockDim.x + threadIdx.x;
    if (e >= E) return;
    int s = ei[e];
    int d = ei[E + e];
    slot_d[e] = atomicAdd(&cnt_dst[d], 1);
    slot_s[e] = atomicAdd(&cnt_src[s], 1);
}

// ---------------- 3-phase exclusive scan ----------------
__global__ __launch_bounds__(256) void scan_phase1(const int* __restrict__ cnt0,
                                                   const int* __restrict__ cnt1,
                                                   int* __restrict__ off0,
                                                   int* __restrict__ off1,
                                                   int* __restrict__ bsum, int N, int CH) {
    int dir = blockIdx.y;
    const int* cnt = dir ? cnt1 : cnt0;
    int* off = dir ? off1 : off0;
    int base = blockIdx.x * CH;
    int end = base + CH; if (end > N) end = N;
    __shared__ int buf[256];
    int carry = 0;
    for (int s = base; s < end; s += 256) {
        int i = s + threadIdx.x;
        int v = (i < end) ? cnt[i] : 0;
        buf[threadIdx.x] = v;
        __syncthreads();
        for (int st = 1; st < 256; st <<= 1) {
            int tv = (threadIdx.x >= st) ? buf[threadIdx.x - st] : 0;
            __syncthreads();
            buf[threadIdx.x] += tv;
            __syncthreads();
        }
        if (i < end) off[i] = carry + buf[threadIdx.x] - v;
        carry += buf[255];
        __syncthreads();
    }
    if (threadIdx.x == 0) bsum[dir * SB + blockIdx.x] = carry;
}

__global__ __launch_bounds__(64) void scan_phase2(int* __restrict__ bsum, int* __restrict__ boff,
                                                  int* __restrict__ off0, int* __restrict__ off1,
                                                  int N) {
    int dir = blockIdx.x;
    __shared__ int buf[SB];
    int v = bsum[dir * SB + threadIdx.x];
    buf[threadIdx.x] = v;
    __syncthreads();
    for (int st = 1; st < SB; st <<= 1) {
        int tv = (threadIdx.x >= st) ? buf[threadIdx.x - st] : 0;
        __syncthreads();
        buf[threadIdx.x] += tv;
        __syncthreads();
    }
    boff[dir * SB + threadIdx.x] = buf[threadIdx.x] - v;
    if (threadIdx.x == SB - 1) {
        int* off = dir ? off1 : off0;
        off[N] = buf[SB - 1];
    }
}

__global__ void scan_phase3(int* __restrict__ off0, int* __restrict__ off1,
                            const int* __restrict__ boff, int N, int CH) {
    int dir = blockIdx.y;
    int* off = dir ? off1 : off0;
    int i = blockIdx.x * 256 + threadIdx.x;
    if (i >= N) return;
    off[i] += boff[dir * SB + i / CH];
}

// ---------------- CSR fill (atomic-free: slots precomputed) ----------------
__global__ void fill_kernel(const int* __restrict__ ei, const int* __restrict__ off_dst,
                            const int* __restrict__ off_src, const int* __restrict__ slot_d,
                            const int* __restrict__ slot_s, int* __restrict__ nbr_dst,
                            int* __restrict__ nbr_src, int E) {
    int e = blockIdx.x * blockDim.x + threadIdx.x;
    if (e >= E) return;
    int s = ei[e];
    int d = ei[E + e];
    nbr_dst[off_dst[d] + slot_d[e]] = s;
    nbr_src[off_src[s] + slot_s[e]] = d;
}

// ---------------- weight prep: transpose + bf16 hi/lo split ----------------
// Whi/Wlo: [96][288] ushort, k-global = m*96 + k; bc = combined bias
__global__ void prep_kernel(const float* __restrict__ Wself, const float* __restrict__ Wsd,
                            const float* __restrict__ Wds, const float* __restrict__ bself,
                            const float* __restrict__ bsd, const float* __restrict__ bds,
                            unsigned short* __restrict__ Whi, unsigned short* __restrict__ Wlo,
                            float* __restrict__ bc) {
    int idx = blockIdx.x * 256 + threadIdx.x;
    if (idx < HF * 288) {
        int j = idx / 288;
        int kk = idx % 288;
        int m = kk / HF, k = kk % HF;
        const float* W = (m == 0) ? Wself : (m == 1) ? Wsd : Wds;
        float w = W[k * HF + j];
        unsigned short hi = f2bf(w);
        float rem = w - bf2f(hi);
        Whi[idx] = hi;
        Wlo[idx] = f2bf(rem);
    } else if (idx < HF * 288 + HF) {
        int j = idx - HF * 288;
        bc[j] = bself[j] + 0.5f * (bsd[j] + bds[j]);
    }
}

// ---------------- x prep: x[N][96] fp32 -> A rows, chunks 0..23 as {hi4,lo4} ----------------
// A layout: [N][72 chunks][8 ushort]; chunk c covers cols 4c..4c+3.
//   chunks  0..23 : h (or x) cols 0..95
//   chunks 24..47 : agg_sd cols (written by gather)
//   chunks 48..71 : agg_ds cols (written by gather)
__global__ __launch_bounds__(256) void xprep_kernel(const float* __restrict__ x,
                                                    unsigned short* __restrict__ Ag, int N) {
    int t = blockIdx.x * 256 + threadIdx.x;
    int n = t / 24, q = t % 24;
    if (n >= N) return;
    float4 v = *(const float4*)(x + (long long)n * HF + q * 4);
    *(uint4*)(Ag + ((long long)n * 576 + q * 8)) = pack_hilo4(v.x, v.y, v.z, v.w);
}

// ---------------- gather-mean (x0.5 ALPHA folded), direction-split, 4-way unrolled ----------
// Reads neighbor h rows (chunks 0..23, 384B contiguous, 24 lanes x 16B = round-0 coalescing),
// reconstructs f = hi+lo, accumulates fp32, writes agg as {hi4,lo4} into chunks 24..71.
__global__ __launch_bounds__(256) void gather_kernel(
        unsigned short* Ag,
        const int* __restrict__ off_dst, const int* __restrict__ nbr_dst,
        const int* __restrict__ off_src, const int* __restrict__ nbr_src, int N) {
    int t = blockIdx.x * blockDim.x + threadIdx.x;
    int n2 = t / 24;
    if (n2 >= 2 * N) return;
    int q = t % 24;
    int dir = (n2 >= N) ? 1 : 0;
    int n = n2 - dir * N;
    const int* off = dir ? off_src : off_dst;
    const int* nbr = dir ? nbr_src : nbr_dst;

    int b = off[n], e = off[n + 1];
    const unsigned short* xq = Ag + q * 8;
    float4 a0 = make_float4(0.f, 0.f, 0.f, 0.f);
    float4 a1 = make_float4(0.f, 0.f, 0.f, 0.f);
    float4 a2 = make_float4(0.f, 0.f, 0.f, 0.f);
    float4 a3 = make_float4(0.f, 0.f, 0.f, 0.f);
    int i = b;
    for (; i + 4 <= e; i += 4) {
        int i0 = nbr[i + 0], i1 = nbr[i + 1], i2 = nbr[i + 2], i3 = nbr[i + 3];
        uint4 w0 = *(const uint4*)(xq + (long long)i0 * 576);
        uint4 w1 = *(const uint4*)(xq + (long long)i1 * 576);
        uint4 w2 = *(const uint4*)(xq + (long long)i2 * 576);
        uint4 w3 = *(const uint4*)(xq + (long long)i3 * 576);
        acc_hilo4(a0, w0);
        acc_hilo4(a1, w1);
        acc_hilo4(a2, w2);
        acc_hilo4(a3, w3);
    }
    for (; i < e; i++) {
        int i0 = nbr[i];
        uint4 w0 = *(const uint4*)(xq + (long long)i0 * 576);
        acc_hilo4(a0, w0);
    }
    float4 acc;
    acc.x = (a0.x + a1.x) + (a2.x + a3.x);
    acc.y = (a0.y + a1.y) + (a2.y + a3.y);
    acc.z = (a0.z + a1.z) + (a2.z + a3.z);
    acc.w = (a0.w + a1.w) + (a2.w + a3.w);
    float inv = 0.5f / fmaxf((float)(e - b), 1.0f);   // ALPHA=0.5 folded (exact pow2 scale)
    acc.x *= inv; acc.y *= inv; acc.z *= inv; acc.w *= inv;
    // write agg chunk: dir 0 -> chunks 24..47, dir 1 -> chunks 48..71
    int chunk = 24 + dir * 24 + q;
    *(uint4*)(Ag + ((long long)n * 576 + chunk * 8)) = pack_hilo4(acc.x, acc.y, acc.z, acc.w);
}

// ---------------- sage GEMM v4: pre-split bf16 hi/lo A (zero-ALU staging) ----------------
// C[N x 96] = relu(A(N x 288, {hi,lo} chunks) @ W(288 x 96) + bc)
// block: 64 rows x 96 cols, 256 thr = 4 waves in 2x2 (wave: 32 rows x 48 cols)
// K-chunks of 32; LDS staging pad 40. Epilogue goes through an aliased LDS f32 tile
// (exactly 25600B) -> vectorized 16B stores. In-place: block reads/writes only its own rows.
#define LPAD 40
__global__ __launch_bounds__(256) void sage_mfma(
        unsigned short* Ag,                 // read chunks 0..71, write chunks 0..23 (mode 0)
        const unsigned short* __restrict__ Whi_g, const unsigned short* __restrict__ Wlo_g,
        const float* __restrict__ bc,
        float* __restrict__ h3, int mode, int N) {   // mode 1: write fp32 h3 instead
    __shared__ __align__(16) unsigned char POOL[25600];
    unsigned short* Ahi = (unsigned short*)POOL;        // 64*LPAD = 2560 us
    unsigned short* Alo = Ahi + 64 * LPAD;
    unsigned short* Whi = Alo + 64 * LPAD;              // 96*LPAD = 3840 us
    unsigned short* Wlo = Whi + 96 * LPAD;
    float* C = (float*)POOL;                            // epilogue alias: 64*100*4 = 25600B

    const int tx = threadIdx.x;
    const int lane = tx & 63;
    const int wid = tx >> 6;
    const int wr = (wid >> 1) * 32;   // wave row offset in block tile
    const int wc = (wid & 1) * 48;    // wave col offset
    const int m = lane & 15;
    const int quad = lane >> 4;
    const int row0 = blockIdx.x * 64;

    // staging indices: 4 threads per row, 2 chunks (16B each) per thread
    const int arow = tx >> 2;         // 0..63
    const int aj = tx & 3;            // 0..3
    int argc = row0 + arow; if (argc > N - 1) argc = N - 1;
    const unsigned short* Arow = Ag + (long long)argc * 576;

    f32x4 acc[2][3];
#pragma unroll
    for (int rt = 0; rt < 2; rt++)
#pragma unroll
        for (int ct = 0; ct < 3; ct++) acc[rt][ct] = (f32x4){0.f, 0.f, 0.f, 0.f};

    for (int kt = 0; kt < 9; kt++) {
        const int kglob = kt * 32;               // k offset in the 288 concat

        // ---- stage A: copy {hi4,lo4} chunks, de-interleave in regs (no ALU conversion)
        {
            const uint4 v0 = *(const uint4*)(Arow + (kt * 8 + aj * 2 + 0) * 8);
            const uint4 v1 = *(const uint4*)(Arow + (kt * 8 + aj * 2 + 1) * 8);
            *(uint2*)&Ahi[arow * LPAD + aj * 8 + 0] = make_uint2(v0.x, v0.y);
            *(uint2*)&Alo[arow * LPAD + aj * 8 + 0] = make_uint2(v0.z, v0.w);
            *(uint2*)&Ahi[arow * LPAD + aj * 8 + 4] = make_uint2(v1.x, v1.y);
            *(uint2*)&Alo[arow * LPAD + aj * 8 + 4] = make_uint2(v1.z, v1.w);
        }
        // ---- stage W: 96x32 bf16 hi/lo, pre-split in global (copy 16B chunks)
        for (int s = tx; s < 384; s += 256) {
            int n = s >> 2, q2 = s & 3;
            long long go = (long long)n * 288 + kglob + q2 * 8;
            *(bf16x8*)&Whi[n * LPAD + q2 * 8] = *(const bf16x8*)(Whi_g + go);
            *(bf16x8*)&Wlo[n * LPAD + q2 * 8] = *(const bf16x8*)(Wlo_g + go);
        }
        __syncthreads();

        // ---- fragments
        bf16x8 ah[2], al[2], bh[3], bl[3];
#pragma unroll
        for (int rt = 0; rt < 2; rt++) {
            int r = (wr + rt * 16 + m) * LPAD + quad * 8;
            ah[rt] = *(const bf16x8*)&Ahi[r];
            al[rt] = *(const bf16x8*)&Alo[r];
        }
#pragma unroll
        for (int ct = 0; ct < 3; ct++) {
            int r = (wc + ct * 16 + m) * LPAD + quad * 8;
            bh[ct] = *(const bf16x8*)&Whi[r];
            bl[ct] = *(const bf16x8*)&Wlo[r];
        }
#pragma unroll
        for (int rt = 0; rt < 2; rt++)
#pragma unroll
            for (int ct = 0; ct < 3; ct++) {
                acc[rt][ct] = __builtin_amdgcn_mfma_f32_16x16x32_bf16(ah[rt], bh[ct], acc[rt][ct], 0, 0, 0);
                acc[rt][ct] = __builtin_amdgcn_mfma_f32_16x16x32_bf16(ah[rt], bl[ct], acc[rt][ct], 0, 0, 0);
                acc[rt][ct] = __builtin_amdgcn_mfma_f32_16x16x32_bf16(al[rt], bh[ct], acc[rt][ct], 0, 0, 0);
            }
        __syncthreads();
    }

    // ---- epilogue: bias + relu into LDS f32 tile (C/D: col=lane&15, row=quad*4+reg)
#pragma unroll
    for (int ct = 0; ct < 3; ct++) {
        int col = wc + ct * 16 + m;
        float bcv = bc[col];
#pragma unroll
        for (int rt = 0; rt < 2; rt++) {
#pragma unroll
            for (int reg = 0; reg < 4; reg++) {
                int rl = wr + rt * 16 + quad * 4 + reg;
                C[rl * 100 + col] = fmaxf(acc[rt][ct][reg] + bcv, 0.f);
            }
        }
    }
    __syncthreads();

    // ---- vectorized store: 4 threads per row, 6 chunks (16B) each
    {
        int rl = tx >> 2;
        int r = row0 + rl;
        if (r < N) {
            if (mode == 0) {
                unsigned short* Orow = Ag + (long long)r * 576;
#pragma unroll
                for (int k = 0; k < 6; k++) {
                    int c = aj * 6 + k;
                    const float* src = &C[rl * 100 + c * 4];
                    *(uint4*)(Orow + c * 8) = pack_hilo4(src[0], src[1], src[2], src[3]);
                }
            } else {
                float* Orow = h3 + (long long)r * HF;
#pragma unroll
                for (int k = 0; k < 6; k++) {
                    int c = aj * 6 + k;
                    *(float4*)(Orow + c * 4) = *(const float4*)&C[rl * 100 + c * 4];
                }
            }
        }
    }
}

// ---------------- segment max pool (batch sorted) ----------------
#define POOL_CHUNK 128
__global__ void pool_kernel(const float* __restrict__ h, const int* __restrict__ batch,
                            unsigned* __restrict__ g, int N) {
    int j = threadIdx.x;
    if (j >= HF) return;
    int n0 = blockIdx.x * POOL_CHUNK;
    int end = n0 + POOL_CHUNK;
    if (end > N) end = N;
    float cur = 0.0f;
    int curb = -1;
    for (int n = n0; n < end; n++) {
        int b = batch[n];
        float v = h[(long long)n * HF + j];
        if (b != curb) {
            if (curb >= 0) atomicMax(&g[curb * HF + j], __float_as_uint(cur));
            curb = b;
            cur = v;
        } else {
            cur = fmaxf(cur, v);
        }
    }
    if (curb >= 0) atomicMax(&g[curb * HF + j], __float_as_uint(cur));
}

// ---------------- final MLP ----------------
__global__ void mlp_kernel(const unsigned* __restrict__ g, const float* __restrict__ lin1_w,
                           const float* __restrict__ lin1_b, const float* __restrict__ lin2_w,
                           const float* __restrict__ lin2_b, float* __restrict__ out) {
    int gi = threadIdx.x;
    if (gi >= GG) return;
    float h5[5];
#pragma unroll
    for (int hh = 0; hh < 5; hh++) {
        float acc = lin1_b[hh];
#pragma unroll 8
        for (int k = 0; k < HF; k++)
            acc = fmaf(__uint_as_float(g[gi * HF + k]), lin1_w[k * 5 + hh], acc);
        h5[hh] = fmaxf(acc, 0.0f);
    }
    float o = lin2_b[0];
#pragma unroll
    for (int hh = 0; hh < 5; hh++) o = fmaf(h5[hh], lin2_w[hh * 1 + 0], o);
    out[gi] = o;
}

extern "C" void kernel_launch(void* const* d_in, const int* in_sizes, int n_in,
                              void* d_out, int out_size, void* d_ws, size_t ws_size,
                              hipStream_t stream) {
    const float* x     = (const float*)d_in[0];
    const int*   ei    = (const int*)d_in[1];
    const int*   batch = (const int*)d_in[2];
    const float* W[3][3];
    const float* B[3][3];
    for (int l = 0; l < 3; l++) {
        for (int t = 0; t < 3; t++) W[l][t] = (const float*)d_in[3 + l * 6 + t];
        for (int t = 0; t < 3; t++) B[l][t] = (const float*)d_in[3 + l * 6 + 3 + t];
    }
    const float* lin1_w = (const float*)d_in[21];
    const float* lin1_b = (const float*)d_in[22];
    const float* lin2_w = (const float*)d_in[23];
    const float* lin2_b = (const float*)d_in[24];

    const int N = in_sizes[0] / HF;
    const int E = in_sizes[1] / 2;

    // workspace layout
    unsigned short* Ag = (unsigned short*)d_ws;          // [N][72][8] us = N*1152 B
    float* h3      = (float*)(Ag + (long long)N * 576);  // [N][96] f32
    int*   cnt_dst = (int*)(h3 + (long long)N * HF);
    int*   cnt_src = cnt_dst + N;
    int*   off_dst = cnt_src + N;           // N+1
    int*   off_src = off_dst + (N + 1);     // N+1
    int*   nbr_dst = off_src + (N + 1);     // E
    int*   nbr_src = nbr_dst + E;           // E
    int*   slot_d  = nbr_src + E;           // E
    int*   slot_s  = slot_d + E;            // E
    int*   bsum    = slot_s + E;            // 2*SB
    int*   boff    = bsum + 2 * SB;         // 2*SB
    float* bc3     = (float*)(boff + 2 * SB);   // 3*96
    // align to 16B for bf16 weight arrays
    uintptr_t p = (uintptr_t)(bc3 + 3 * HF);
    p = (p + 15) & ~(uintptr_t)15;
    unsigned short* Whi3 = (unsigned short*)p;          // 3 * 96*288
    unsigned short* Wlo3 = Whi3 + 3 * HF * 288;         // 3 * 96*288
    uintptr_t p2 = (uintptr_t)(Wlo3 + 3 * HF * 288);
    p2 = (p2 + 15) & ~(uintptr_t)15;
    unsigned* g = (unsigned*)p2;

    hipMemsetAsync(cnt_dst, 0, (size_t)2 * N * sizeof(int), stream);
    hipMemsetAsync(g, 0, (size_t)GG * HF * sizeof(unsigned), stream);

    // weight prep (independent of graph build)
    const int prep_blocks = (HF * 288 + HF + 255) / 256;
    for (int l = 0; l < 3; l++)
        prep_kernel<<<prep_blocks, 256, 0, stream>>>(
            W[l][0], W[l][1], W[l][2], B[l][0], B[l][1], B[l][2],
            Whi3 + (long long)l * HF * 288, Wlo3 + (long long)l * HF * 288, bc3 + l * HF);

    // x -> hi/lo chunks of A
    xprep_kernel<<<(N * 24 + 255) / 256, 256, 0, stream>>>(x, Ag, N);

    const int CH = (N + SB - 1) / SB;
    count_kernel<<<(E + 255) / 256, 256, 0, stream>>>(ei, cnt_dst, cnt_src, slot_d, slot_s, E);
    scan_phase1<<<dim3(SB, 2), 256, 0, stream>>>(cnt_dst, cnt_src, off_dst, off_src, bsum, N, CH);
    scan_phase2<<<2, SB, 0, stream>>>(bsum, boff, off_dst, off_src, N);
    scan_phase3<<<dim3((N + 255) / 256, 2), 256, 0, stream>>>(off_dst, off_src, boff, N, CH);
    fill_kernel<<<(E + 255) / 256, 256, 0, stream>>>(ei, off_dst, off_src,
                                                     slot_d, slot_s, nbr_dst, nbr_src, E);

    const long long gather_threads = (long long)2 * N * 24;
    const int gather_blocks = (int)((gather_threads + 255) / 256);
    const int gemm_blocks = (N + 63) / 64;
    const int pool_blocks = (N + POOL_CHUNK - 1) / POOL_CHUNK;

    for (int l = 0; l < 3; l++) {
        gather_kernel<<<gather_blocks, 256, 0, stream>>>(
            Ag, off_dst, nbr_dst, off_src, nbr_src, N);
        sage_mfma<<<gemm_blocks, 256, 0, stream>>>(
            Ag,
            Whi3 + (long long)l * HF * 288, Wlo3 + (long long)l * HF * 288,
            bc3 + l * HF, h3, (l < 2) ? 0 : 1, N);
    }

    pool_kernel<<<pool_blocks, 128, 0, stream>>>(h3, batch, g, N);
    mlp_kernel<<<1, 64, 0, stream>>>(g, lin1_w, lin1_b, lin2_w, lin2_b, (float*)d_out);
}